// Round 6
// baseline (81.869 us; speedup 1.0000x reference)
//
#include <hip/hip_runtime.h>
#include <math.h>

// Problem constants (match reference: B,T,C,H = 16,1024,2048,16)
#define BB 16
#define TT 1024
#define CC 2048

constexpr int L    = 32;   // output chunk length (time steps)
constexpr int HALO = 16;   // warm-up: min decay e^{-0.5*16}=3.4e-4 -> y err ~1e-3 << 0.108
constexpr int PF   = 8;    // prefetch depth (double-buffered)
constexpr int C4   = CC / 4;  // row stride in float4 units (512)

typedef float f32x4 __attribute__((ext_vector_type(4)));

template<int N, bool STORE>
__device__ __forceinline__ void scan4(
    const f32x4* __restrict__ kp, const f32x4* __restrict__ vp,
    f32x4* __restrict__ yp, f32x4& p, f32x4& q,
    float ew, float eu)
{
    f32x4 kA[PF], vA[PF], kB[PF], vB[PF];
#pragma unroll
    for (int i = 0; i < PF; ++i) { kA[i] = kp[i * C4]; vA[i] = vp[i * C4]; }

    auto step = [&](f32x4 kt, f32x4 vt, int t) {
        f32x4 ek;
#pragma unroll
        for (int e = 0; e < 4; ++e) ek[e] = __expf(kt[e]);   // off-chain
        if (STORE) {
            f32x4 Bc  = eu * ek;            // e^{u+k_t}
            f32x4 num = Bc * vt + p;
            f32x4 den = q + Bc;
            f32x4 out;
#pragma unroll
            for (int e = 0; e < 4; ++e) out[e] = __fdividef(num[e], den[e]);
            __builtin_nontemporal_store(out, &yp[t * C4]);  // y never re-read
        }
        p = ew * p + ek * vt;               // carried: 1 FMA per component
        q = ew * q + ek;                    // carried: 1 FMA per component
    };

#pragma unroll
    for (int t0 = 0; t0 < N; t0 += 2 * PF) {
#pragma unroll
        for (int i = 0; i < PF; ++i) {
            kB[i] = kp[(t0 + PF + i) * C4];
            vB[i] = vp[(t0 + PF + i) * C4];
        }
#pragma unroll
        for (int i = 0; i < PF; ++i) step(kA[i], vA[i], t0 + i);
        if (t0 + 2 * PF < N) {
#pragma unroll
            for (int i = 0; i < PF; ++i) {
                kA[i] = kp[(t0 + 2 * PF + i) * C4];
                vA[i] = vp[(t0 + 2 * PF + i) * C4];
            }
        }
#pragma unroll
        for (int i = 0; i < PF; ++i) step(kB[i], vB[i], t0 + PF + i);
    }
}

__global__ __launch_bounds__(256, 1) void wkv_row_kernel(
    const float* __restrict__ x,     // v  [B,T,C]
    const float* __restrict__ gate,  // k  [B,T,C]
    const float* __restrict__ bw,    // beta_w_under [H]
    const float* __restrict__ bu,    // beta_u_under [H]
    float* __restrict__ y)           // out [B,T,C]
{
    // Block covers a contiguous half C-row (1024 channels = 4 KB); each
    // t-step's block-level load is 4 KB contiguous from each of k and v,
    // streaming sequentially through memory.
    // bid layout: chunk j in LOW bits -> chunk j's halo == chunk j-1's tail
    // are dispatch-adjacent (L2/L3 timing locality for the re-reads).
    const int bid = blockIdx.x;
    const int j   = bid & 31;            // 32 T-chunks of 32
    const int ch  = (bid >> 5) & 1;      // which half of the C row
    const int b   = bid >> 6;            // batch 0..15

    const int c4  = ch * 256 + threadIdx.x;  // float4-column, 0..511
    const int c0  = c4 * 4;                  // first channel of this thread
    const int h   = c0 >> 7;                 // head (4-ch group never straddles)

    const float w  = -fabsf(bw[h]) * 10.0f;   // in [-5,-0.5]
    const float u  =  fabsf(bu[h]) * 10.0f;
    const float ew = __expf(w);
    const float eu = __expf(u);

    const int t0   = j * L;
    const int base = b * TT * C4 + c4;        // in float4 units

    const f32x4* kp = (const f32x4*)gate + base;
    const f32x4* vp = (const f32x4*)x    + base;
    f32x4*       yp = (f32x4*)y          + base;

    f32x4 p = {0.f, 0.f, 0.f, 0.f};
    f32x4 q = {0.f, 0.f, 0.f, 0.f};

    if (j > 0) {  // block-uniform branch
        const int ts = t0 - HALO;
        scan4<HALO, false>(kp + ts * C4, vp + ts * C4, nullptr, p, q, ew, eu);
    }
    scan4<L, true>(kp + t0 * C4, vp + t0 * C4, yp + t0 * C4, p, q, ew, eu);
}

extern "C" void kernel_launch(void* const* d_in, const int* in_sizes, int n_in,
                              void* d_out, int out_size, void* d_ws, size_t ws_size,
                              hipStream_t stream) {
    const float* x    = (const float*)d_in[0];  // v
    const float* gate = (const float*)d_in[1];  // k
    const float* bw   = (const float*)d_in[2];
    const float* bu   = (const float*)d_in[3];
    float* y = (float*)d_out;

    // 16 batches x 2 half-rows x 32 chunks = 1024 blocks of 256 threads
    const int grid = BB * 2 * (TT / L);
    wkv_row_kernel<<<grid, 256, 0, stream>>>(x, gate, bw, bu, y);
}

// Round 7
// 66.229 us; speedup vs baseline: 1.2361x; 1.2361x over previous
//
#include <hip/hip_runtime.h>
#include <math.h>

// Problem constants (match reference: B,T,C,H = 16,1024,2048,16)
#define BB 16
#define TT 1024
#define CC 2048

constexpr int L  = 64;      // output chunk length (time steps)
constexpr int C4 = CC / 4;  // row stride in float4 units (512)

typedef float f32x4 __attribute__((ext_vector_type(4)));

// Generic double-buffered scan over N steps. PFE is compile-time so all
// register arrays are statically indexed (no scratch).
template<int N, bool STORE>
__device__ __forceinline__ void scan4(
    const f32x4* __restrict__ kp, const f32x4* __restrict__ vp,
    f32x4* __restrict__ yp, f32x4& p, f32x4& q,
    float ew, float eu)
{
    constexpr int PFE = (N >= 16) ? 8 : (N / 2);
    f32x4 kA[PFE], vA[PFE], kB[PFE], vB[PFE];
#pragma unroll
    for (int i = 0; i < PFE; ++i) { kA[i] = kp[i * C4]; vA[i] = vp[i * C4]; }

    auto step = [&](f32x4 kt, f32x4 vt, int t) {
        f32x4 ek;
#pragma unroll
        for (int e = 0; e < 4; ++e) ek[e] = __expf(kt[e]);   // off-chain
        if (STORE) {
            f32x4 Bc  = eu * ek;            // e^{u+k_t}
            f32x4 num = Bc * vt + p;
            f32x4 den = q + Bc;
            f32x4 out;
#pragma unroll
            for (int e = 0; e < 4; ++e) out[e] = __fdividef(num[e], den[e]);
            __builtin_nontemporal_store(out, &yp[t * C4]);  // y never re-read
        }
        p = ew * p + ek * vt;               // carried: 1 FMA per component
        q = ew * q + ek;                    // carried: 1 FMA per component
    };

#pragma unroll
    for (int t0 = 0; t0 < N; t0 += 2 * PFE) {
#pragma unroll
        for (int i = 0; i < PFE; ++i) {
            kB[i] = kp[(t0 + PFE + i) * C4];
            vB[i] = vp[(t0 + PFE + i) * C4];
        }
#pragma unroll
        for (int i = 0; i < PFE; ++i) step(kA[i], vA[i], t0 + i);
        if (t0 + 2 * PFE < N) {
#pragma unroll
            for (int i = 0; i < PFE; ++i) {
                kA[i] = kp[(t0 + 2 * PFE + i) * C4];
                vA[i] = vp[(t0 + 2 * PFE + i) * C4];
            }
        }
#pragma unroll
        for (int i = 0; i < PFE; ++i) step(kB[i], vB[i], t0 + PFE + i);
    }
}

__global__ __launch_bounds__(256, 1) void wkv_row_kernel(
    const float* __restrict__ x,     // v  [B,T,C]
    const float* __restrict__ gate,  // k  [B,T,C]
    const float* __restrict__ bw,    // beta_w_under [H]
    const float* __restrict__ bu,    // beta_u_under [H]
    float* __restrict__ y)           // out [B,T,C]
{
    // Block covers a contiguous half C-row (1024 channels = 4 KB); each
    // t-step's block-level load is 4 KB contiguous from each of k and v.
    // bid layout: chunk j in LOW bits -> chunk j's halo == chunk j-1's tail
    // are dispatch-adjacent (cache timing locality for the re-reads).
    const int bid = blockIdx.x;
    const int j   = bid & 15;            // 16 T-chunks of 64
    const int ch  = (bid >> 4) & 1;      // which half of the C row
    const int b   = bid >> 5;            // batch 0..15

    const int c4  = ch * 256 + threadIdx.x;  // float4-column, 0..511
    const int c0  = c4 * 4;                  // first channel of this thread
    const int h   = c0 >> 7;                 // head (4-ch group never straddles)

    const float w  = -fabsf(bw[h]) * 10.0f;   // in [-5,-0.5]
    const float u  =  fabsf(bu[h]) * 10.0f;
    const float ew = __expf(w);
    const float eu = __expf(u);

    const int t0   = j * L;
    const int base = b * TT * C4 + c4;        // in float4 units

    const f32x4* kp = (const f32x4*)gate + base;
    const f32x4* vp = (const f32x4*)x    + base;
    f32x4*       yp = (f32x4*)y          + base;

    f32x4 p = {0.f, 0.f, 0.f, 0.f};
    f32x4 q = {0.f, 0.f, 0.f, 0.f};

    if (j > 0) {  // block-uniform branch
        // Per-wave adaptive halo: wave spans exactly 2 heads (256 ch);
        // the slower head (smaller |w|, lower h) sets the warm-up length.
        // Need H >= 6.5/|w|  (truncation weight e^{-6.5} ~ 1.5e-3).
        const int  h_lo  = (ch * 1024 + (threadIdx.x & ~63) * 4) >> 7;
        const float wlo  = fabsf(bw[h_lo]) * 10.0f;   // |w| of slower head
        const float need = 6.5f / wlo;                 // wave-uniform

        if (need > 8.0f) {
            scan4<16, false>(kp + (t0 - 16) * C4, vp + (t0 - 16) * C4,
                             nullptr, p, q, ew, eu);
        } else if (need > 4.0f) {
            scan4<8, false>(kp + (t0 - 8) * C4, vp + (t0 - 8) * C4,
                            nullptr, p, q, ew, eu);
        } else if (need > 2.0f) {
            scan4<4, false>(kp + (t0 - 4) * C4, vp + (t0 - 4) * C4,
                            nullptr, p, q, ew, eu);
        } else {
            scan4<2, false>(kp + (t0 - 2) * C4, vp + (t0 - 2) * C4,
                            nullptr, p, q, ew, eu);
        }
    }
    scan4<L, true>(kp + t0 * C4, vp + t0 * C4, yp + t0 * C4, p, q, ew, eu);
}

extern "C" void kernel_launch(void* const* d_in, const int* in_sizes, int n_in,
                              void* d_out, int out_size, void* d_ws, size_t ws_size,
                              hipStream_t stream) {
    const float* x    = (const float*)d_in[0];  // v
    const float* gate = (const float*)d_in[1];  // k
    const float* bw   = (const float*)d_in[2];
    const float* bu   = (const float*)d_in[3];
    float* y = (float*)d_out;

    // 16 batches x 2 half-rows x 16 chunks = 512 blocks of 256 threads
    const int grid = BB * 2 * (TT / L);
    wkv_row_kernel<<<grid, 256, 0, stream>>>(x, gate, bw, bu, y);
}

// Round 8
// 65.837 us; speedup vs baseline: 1.2435x; 1.0060x over previous
//
#include <hip/hip_runtime.h>
#include <math.h>

// Problem constants (match reference: B,T,C,H = 16,1024,2048,16)
#define BB 16
#define TT 1024
#define CC 2048

constexpr int L  = 128;     // output chunk length (time steps)
constexpr int C4 = CC / 4;  // row stride in float4 units (512)

typedef float f32x4 __attribute__((ext_vector_type(4)));

// Generic double-buffered scan over N steps. PFE is compile-time so all
// register arrays are statically indexed (no scratch).
template<int N, bool STORE>
__device__ __forceinline__ void scan4(
    const f32x4* __restrict__ kp, const f32x4* __restrict__ vp,
    f32x4* __restrict__ yp, f32x4& p, f32x4& q,
    float ew, float eu)
{
    constexpr int PFE = (N >= 16) ? 8 : (N / 2);
    f32x4 kA[PFE], vA[PFE], kB[PFE], vB[PFE];
#pragma unroll
    for (int i = 0; i < PFE; ++i) { kA[i] = kp[i * C4]; vA[i] = vp[i * C4]; }

    auto step = [&](f32x4 kt, f32x4 vt, int t) {
        f32x4 ek;
#pragma unroll
        for (int e = 0; e < 4; ++e) ek[e] = __expf(kt[e]);   // off-chain
        if (STORE) {
            f32x4 Bc  = eu * ek;            // e^{u+k_t}
            f32x4 num = Bc * vt + p;
            f32x4 den = q + Bc;
            f32x4 out;
#pragma unroll
            for (int e = 0; e < 4; ++e) out[e] = __fdividef(num[e], den[e]);
            __builtin_nontemporal_store(out, &yp[t * C4]);  // y never re-read
        }
        p = ew * p + ek * vt;               // carried: 1 FMA per component
        q = ew * q + ek;                    // carried: 1 FMA per component
    };

#pragma unroll
    for (int t0 = 0; t0 < N; t0 += 2 * PFE) {
#pragma unroll
        for (int i = 0; i < PFE; ++i) {
            kB[i] = kp[(t0 + PFE + i) * C4];
            vB[i] = vp[(t0 + PFE + i) * C4];
        }
#pragma unroll
        for (int i = 0; i < PFE; ++i) step(kA[i], vA[i], t0 + i);
        if (t0 + 2 * PFE < N) {
#pragma unroll
            for (int i = 0; i < PFE; ++i) {
                kA[i] = kp[(t0 + 2 * PFE + i) * C4];
                vA[i] = vp[(t0 + 2 * PFE + i) * C4];
            }
        }
#pragma unroll
        for (int i = 0; i < PFE; ++i) step(kB[i], vB[i], t0 + PFE + i);
    }
}

__global__ __launch_bounds__(256, 1) void wkv_row_kernel(
    const float* __restrict__ x,     // v  [B,T,C]
    const float* __restrict__ gate,  // k  [B,T,C]
    const float* __restrict__ bw,    // beta_w_under [H]
    const float* __restrict__ bu,    // beta_u_under [H]
    float* __restrict__ y)           // out [B,T,C]
{
    // Block covers a contiguous half C-row (1024 channels = 4 KB); each
    // t-step's block-level load is 4 KB contiguous from each of k and v.
    // bid layout: chunk j in LOW bits -> chunk j's halo == chunk j-1's tail
    // are dispatch-adjacent (cache timing locality for the re-reads).
    const int bid = blockIdx.x;
    const int j   = bid & 7;             // 8 T-chunks of 128
    const int ch  = (bid >> 3) & 1;      // which half of the C row
    const int b   = bid >> 4;            // batch 0..15

    const int c4  = ch * 256 + threadIdx.x;  // float4-column, 0..511
    const int c0  = c4 * 4;                  // first channel of this thread
    const int h   = c0 >> 7;                 // head (4-ch group never straddles)

    const float w  = -fabsf(bw[h]) * 10.0f;   // in [-5,-0.5]
    const float u  =  fabsf(bu[h]) * 10.0f;
    const float ew = __expf(w);
    const float eu = __expf(u);

    const int t0   = j * L;
    const int base = b * TT * C4 + c4;        // in float4 units

    const f32x4* kp = (const f32x4*)gate + base;
    const f32x4* vp = (const f32x4*)x    + base;
    f32x4*       yp = (f32x4*)y          + base;

    f32x4 p = {0.f, 0.f, 0.f, 0.f};
    f32x4 q = {0.f, 0.f, 0.f, 0.f};

    if (j > 0) {  // block-uniform branch
        // Per-wave adaptive halo: wave spans exactly 2 heads (256 ch);
        // the slower head (smaller |w|, lower h) sets the warm-up length.
        // Need H >= 6.5/|w|  (truncation weight e^{-6.5} ~ 1.5e-3).
        const int  h_lo  = (ch * 1024 + (threadIdx.x & ~63) * 4) >> 7;
        const float wlo  = fabsf(bw[h_lo]) * 10.0f;   // |w| of slower head
        const float need = 6.5f / wlo;                 // wave-uniform

        if (need > 8.0f) {
            scan4<16, false>(kp + (t0 - 16) * C4, vp + (t0 - 16) * C4,
                             nullptr, p, q, ew, eu);
        } else if (need > 4.0f) {
            scan4<8, false>(kp + (t0 - 8) * C4, vp + (t0 - 8) * C4,
                            nullptr, p, q, ew, eu);
        } else if (need > 2.0f) {
            scan4<4, false>(kp + (t0 - 4) * C4, vp + (t0 - 4) * C4,
                            nullptr, p, q, ew, eu);
        } else {
            scan4<2, false>(kp + (t0 - 2) * C4, vp + (t0 - 2) * C4,
                            nullptr, p, q, ew, eu);
        }
    }
    scan4<L, true>(kp + t0 * C4, vp + t0 * C4, yp + t0 * C4, p, q, ew, eu);
}

extern "C" void kernel_launch(void* const* d_in, const int* in_sizes, int n_in,
                              void* d_out, int out_size, void* d_ws, size_t ws_size,
                              hipStream_t stream) {
    const float* x    = (const float*)d_in[0];  // v
    const float* gate = (const float*)d_in[1];  // k
    const float* bw   = (const float*)d_in[2];
    const float* bu   = (const float*)d_in[3];
    float* y = (float*)d_out;

    // 16 batches x 2 half-rows x 8 chunks = 256 blocks of 256 threads
    const int grid = BB * 2 * (TT / L);
    wkv_row_kernel<<<grid, 256, 0, stream>>>(x, gate, bw, bu, y);
}